// Round 6
// baseline (230.324 us; speedup 1.0000x reference)
//
#include <hip/hip_runtime.h>
#include <hip/hip_bf16.h>

// ws layout (floats):
//   [128..202]       quantized w_conv (75)
//   [256..44287]     quantized w_fc1 QUAD-BLOCKED: w1b[jq][o][4], jq=0..85
//                    element (o,j) at 256 + (j>>2)*512 + 4*o + (j&3)
//                    (j=343 pad slots never written; multiplied by feat[343]=0)
//   [44288..44799]   quantized w_fc2 [4][128]
#define WS_WCONV   128
#define WS_W1B     256
#define WS_W2      44288

__device__ __forceinline__ float q4(float w, float s) {
  if (s <= 0.f) return 0.f;
  float r = rintf(w / s);                     // round-half-even == jnp.round
  r = fminf(fmaxf(r, -8.f), 7.f);
  return r * s;
}

// Single quant dispatch (R3/R4-proven, absmax 0), now writing the
// quad-blocked FC1 layout.
__global__ __launch_bounds__(256) void quant_all(
    const float* __restrict__ wconv, const float* __restrict__ w1,
    const float* __restrict__ w2, float* __restrict__ ws) {
  __shared__ float red[256];
  int b = blockIdx.x, t = threadIdx.x;
  if (b < 88) {
    const float4* w4 = (const float4*)w1;     // 43904/4 == 10976
    float m = 0.f;
    for (int i = t; i < 10976; i += 256) {
      float4 v = w4[i];
      m = fmaxf(m, fmaxf(fmaxf(fabsf(v.x), fabsf(v.y)),
                         fmaxf(fabsf(v.z), fabsf(v.w))));
    }
    red[t] = m;
    __syncthreads();
    for (int s = 128; s > 0; s >>= 1) {
      if (t < s) red[t] = fmaxf(red[t], red[t + s]);
      __syncthreads();
    }
    float s = red[0] * (1.0f / 7.0f);
    #pragma unroll
    for (int k = 0; k < 2; ++k) {
      int idx = b * 512 + k * 256 + t;
      if (idx < 43904) {
        float q = q4(w1[idx], s);
        int o = idx / 343;
        int j = idx - o * 343;
        ws[WS_W1B + (j >> 2) * 512 + 4 * o + (j & 3)] = q;
      }
    }
  } else {
    float mc = (t < 75) ? fabsf(wconv[t]) : 0.f;
    float m2 = 0.f;
    for (int i = t; i < 512; i += 256) m2 = fmaxf(m2, fabsf(w2[i]));
    red[t] = mc;
    __syncthreads();
    for (int s = 128; s > 0; s >>= 1) {
      if (t < s) red[t] = fmaxf(red[t], red[t + s]);
      __syncthreads();
    }
    float sc = red[0] * (1.0f / 7.0f);
    __syncthreads();
    red[t] = m2;
    __syncthreads();
    for (int s = 128; s > 0; s >>= 1) {
      if (t < s) red[t] = fmaxf(red[t], red[t + s]);
      __syncthreads();
    }
    float s2 = red[0] * (1.0f / 7.0f);
    if (t < 75) ws[WS_WCONV + t] = q4(wconv[t], sc);
    #pragma unroll
    for (int k = 0; k < 2; ++k) {
      int idx = k * 256 + t;
      ws[WS_W2 + idx] = q4(w2[idx], s2);
    }
  }
}

// Flat float4 staging of ndep depths starting at global depth d0 (R4-style:
// zero index math, coalesced 16B).
__device__ __forceinline__ void stage(
    const float* __restrict__ x, int b, int d0, int ndep,
    float* __restrict__ xs, int t) {
  const float4* src = (const float4*)(x + (size_t)b * 15376 + d0 * 496);
  float4* dst = (float4*)xs;
  int n = ndep * 124;                         // 496/4
  for (int i = t; i < n; i += 256) dst[i] = src[i];
}

// Conv for 2 pooled-depth rows (or 1 for the last chunk). xs holds local
// depths 0..ndep-1 = global d0..; pd = pd_off + pdl, local depth 4*pdl+dd.
__device__ __forceinline__ void conv_phase(
    const float* __restrict__ xs, const float* __restrict__ wq,
    int t, int npf, int pd_off, float bc, float* __restrict__ feat) {
  if (t >= npf) return;
  int pdl = t / 49;
  int rr  = t - pdl * 49;
  int ph  = rr / 7;
  int pw  = rr - ph * 7;
  float c[2][2][2];                           // [odp][ohp][owp]
  #pragma unroll
  for (int i = 0; i < 8; ++i) ((float*)c)[i] = 0.f;
  int base0 = pdl * 1984 + ph * 62 + pw * 4;  // 1984 = 4*496, 62 = 2*31
  #pragma unroll
  for (int dd = 0; dd < 7; ++dd) {
    int rbase = base0 + dd * 496;
    #pragma unroll
    for (int hh = 0; hh < 4; ++hh) {
      float row[7];
      #pragma unroll
      for (int wi = 0; wi < 7; ++wi) row[wi] = xs[rbase + hh * 31 + wi];
      #pragma unroll
      for (int odp = 0; odp < 2; ++odp) {
        int kd = dd - 2 * odp;
        if (kd < 0 || kd > 4) continue;       // folds at compile time
        #pragma unroll
        for (int ohp = 0; ohp < 2; ++ohp) {
          int kh = hh - ohp;
          if (kh < 0 || kh > 2) continue;     // folds at compile time
          #pragma unroll
          for (int owp = 0; owp < 2; ++owp) {
            float a = c[odp][ohp][owp];
            #pragma unroll
            for (int kw = 0; kw < 5; ++kw)
              a = fmaf(row[2 * owp + kw], wq[kd * 15 + kh * 5 + kw], a);
            c[odp][ohp][owp] = a;
          }
        }
      }
    }
  }
  float m = ((float*)c)[0];
  #pragma unroll
  for (int i = 1; i < 8; ++i) m = fmaxf(m, ((float*)c)[i]);
  feat[(pdl + pd_off) * 49 + rr] = m + bc;
}

// Fused net v6: 4 depth chunks (11/11/11/7 depths, pd pairs) -> LDS 23.2KB
// -> 6-7 blocks/CU (vs 4). Odd blocks walk chunks in REVERSE order to
// de-synchronize co-resident blocks' stage(VMEM) vs conv(VALU) phases.
// FC1 reads w1 quad-blocked: one float4 = 4 j-terms -> 43 loads/thread
// (was 172), 4x shorter load chain.
__global__ __launch_bounds__(256, 6) void fused_net(
    const float* __restrict__ x, const float* __restrict__ bconv,
    const float* __restrict__ ws, const float* __restrict__ bfc1,
    const float* __restrict__ bfc2, float* __restrict__ out) {
  __shared__ float xs[5456];                  // 11 depths * 496
  __shared__ float feat[344];                 // +1: feat[343]=0 pads FC1 quads
  float* fc1p = xs;                           // aliases: used only after conv
  float* a1   = xs + 128;
  float* s2   = xs + 256;
  int t = threadIdx.x;
  int b = blockIdx.x;
  const float* wq = ws + WS_WCONV;
  float bc = bconv[0];

  if (t == 0) feat[343] = 0.f;
  int par = b & 1;
  #pragma unroll
  for (int ci = 0; ci < 4; ++ci) {
    int c = par ? (3 - ci) : ci;              // stagger chunk order by parity
    int d0 = 8 * c;
    int ndep = (c == 3) ? 7 : 11;
    stage(x, b, d0, ndep, xs, t);
    __syncthreads();
    conv_phase(xs, wq, t, (c == 3) ? 49 : 98, 2 * c, bc, feat);
    __syncthreads();
  }

  // FC1 (343->128): g = j-half (43 quads each), o = output.
  // feat read as b128 broadcast; w1b read as one coalesced float4 per quad.
  int g = t >> 7, o = t & 127;
  {
    const float* w1b = ws + WS_W1B;
    int q0 = g ? 43 : 0;
    const float4* f4 = (const float4*)feat;
    float p0 = 0.f, p1 = 0.f, p2 = 0.f, p3 = 0.f;
    for (int q = q0; q < q0 + 43; ++q) {
      float4 f = f4[q];
      float4 w = *(const float4*)&w1b[q * 512 + 4 * o];
      p0 = fmaf(f.x, w.x, p0);
      p1 = fmaf(f.y, w.y, p1);
      p2 = fmaf(f.z, w.z, p2);
      p3 = fmaf(f.w, w.w, p3);
    }
    float acc = (p0 + p1) + (p2 + p3);
    if (g) fc1p[o] = acc;
    __syncthreads();
    if (!g) a1[o] = fmaxf(acc + fc1p[o] + bfc1[o], 0.f);
  }
  __syncthreads();

  // FC2 (128->4) on one wave: lane = (kk,cls); float4 reads; shuffle-reduce.
  if (t < 64) {
    int cls = t & 3, kk = t >> 2;             // kk 0..15, 8 k's each
    const float4* w2 = (const float4*)(ws + WS_W2 + cls * 128 + kk * 8);
    const float4* av = (const float4*)(a1 + kk * 8);
    float4 aa = av[0], ab = av[1], wa = w2[0], wb = w2[1];
    float p = 0.f;
    p = fmaf(aa.x, wa.x, p); p = fmaf(aa.y, wa.y, p);
    p = fmaf(aa.z, wa.z, p); p = fmaf(aa.w, wa.w, p);
    p = fmaf(ab.x, wb.x, p); p = fmaf(ab.y, wb.y, p);
    p = fmaf(ab.z, wb.z, p); p = fmaf(ab.w, wb.w, p);
    p += __shfl_down(p, 32);
    p += __shfl_down(p, 16);
    p += __shfl_down(p, 8);
    p += __shfl_down(p, 4);
    if (t < 4) s2[t] = p + bfc2[t];
  }
  __syncthreads();
  // softmax + store
  if (t < 4) {
    float v0 = s2[0], v1 = s2[1], v2 = s2[2], v3 = s2[3];
    float m = fmaxf(fmaxf(v0, v1), fmaxf(v2, v3));
    float e0 = expf(v0 - m), e1 = expf(v1 - m);
    float e2 = expf(v2 - m), e3 = expf(v3 - m);
    float inv = 1.f / (e0 + e1 + e2 + e3);
    float mine = (t == 0) ? e0 : (t == 1) ? e1 : (t == 2) ? e2 : e3;
    out[b * 4 + t] = mine * inv;
  }
}

extern "C" void kernel_launch(void* const* d_in, const int* in_sizes, int n_in,
                              void* d_out, int out_size, void* d_ws, size_t ws_size,
                              hipStream_t stream) {
  const float* x     = (const float*)d_in[0];
  const float* wconv = (const float*)d_in[1];
  const float* bconv = (const float*)d_in[2];
  const float* wfc1  = (const float*)d_in[3];
  const float* bfc1  = (const float*)d_in[4];
  const float* wfc2  = (const float*)d_in[5];
  const float* bfc2  = (const float*)d_in[6];
  float* out = (float*)d_out;
  float* ws  = (float*)d_ws;

  quant_all<<<89, 256, 0, stream>>>(wconv, wfc1, wfc2, ws);
  fused_net<<<2048, 256, 0, stream>>>(x, bconv, ws, bfc1, bfc2, out);
}